// Round 1
// baseline (1357.560 us; speedup 1.0000x reference)
//
#include <hip/hip_runtime.h>
#include <cstddef>
#include <cstdint>

#define N_NODES   100000
#define N_EDGES   1600000
#define N_GRAPHS  512
#define HIDDEN    128
#define N_LAYERS  3

// ---------------------------------------------------------------------------
// CSR build (by dst): histogram -> single-block scan -> scatter
// ---------------------------------------------------------------------------
__global__ void deg_kernel(const int* __restrict__ dst, int* __restrict__ deg) {
    int e = blockIdx.x * blockDim.x + threadIdx.x;
    if (e < N_EDGES) atomicAdd(&deg[dst[e]], 1);
}

__global__ __launch_bounds__(1024) void scan_kernel(const int* __restrict__ deg,
                                                    int* __restrict__ row_ptr) {
    __shared__ int sums[1024];
    const int t = threadIdx.x;
    const int C = (N_NODES + 1023) / 1024;  // 98
    int lo = t * C, hi = lo + C;
    if (hi > N_NODES) hi = N_NODES;
    int s = 0;
    for (int i = lo; i < hi; ++i) s += deg[i];
    sums[t] = s;
    __syncthreads();
    // Hillis-Steele inclusive scan over 1024 partials
    for (int off = 1; off < 1024; off <<= 1) {
        int v = (t >= off) ? sums[t - off] : 0;
        __syncthreads();
        sums[t] += v;
        __syncthreads();
    }
    int run = (t == 0) ? 0 : sums[t - 1];  // exclusive prefix for this chunk
    for (int i = lo; i < hi; ++i) { run += deg[i]; row_ptr[i + 1] = run; }
    if (t == 0) row_ptr[0] = 0;
}

__global__ void scatter_kernel(const int* __restrict__ src, const int* __restrict__ dst,
                               int* __restrict__ pos, int* __restrict__ csr_src) {
    int e = blockIdx.x * blockDim.x + threadIdx.x;
    if (e < N_EDGES) {
        int p = atomicAdd(&pos[dst[e]], 1);
        csr_src[p] = src[e];
    }
}

// ---------------------------------------------------------------------------
// GIN aggregation: Z[i] = X[i] + sum_{j in N_in(i)} X[j]
// one wave (64 lanes) per node, float2 per lane => 512B coalesced row reads
// ---------------------------------------------------------------------------
__global__ void gather_kernel(const float* __restrict__ X, float* __restrict__ Z,
                              const int* __restrict__ row_ptr,
                              const int* __restrict__ csr_src) {
    int wave = (blockIdx.x * blockDim.x + threadIdx.x) >> 6;
    int lane = threadIdx.x & 63;
    if (wave >= N_NODES) return;
    const int i = wave;
    float2 acc = ((const float2*)(X + (size_t)i * HIDDEN))[lane];
    int k = row_ptr[i];
    const int end = row_ptr[i + 1];
    // 4-deep unroll: 4 independent row loads in flight to hide LLC latency
    for (; k + 4 <= end; k += 4) {
        int n0 = csr_src[k + 0];
        int n1 = csr_src[k + 1];
        int n2 = csr_src[k + 2];
        int n3 = csr_src[k + 3];
        float2 v0 = ((const float2*)(X + (size_t)n0 * HIDDEN))[lane];
        float2 v1 = ((const float2*)(X + (size_t)n1 * HIDDEN))[lane];
        float2 v2 = ((const float2*)(X + (size_t)n2 * HIDDEN))[lane];
        float2 v3 = ((const float2*)(X + (size_t)n3 * HIDDEN))[lane];
        acc.x += v0.x + v1.x + v2.x + v3.x;
        acc.y += v0.y + v1.y + v2.y + v3.y;
    }
    for (; k < end; ++k) {
        int n = csr_src[k];
        float2 v = ((const float2*)(X + (size_t)n * HIDDEN))[lane];
        acc.x += v.x;
        acc.y += v.y;
    }
    ((float2*)(Z + (size_t)i * HIDDEN))[lane] = acc;
}

// ---------------------------------------------------------------------------
// C[M x 128] = relu(A[M x 128] @ W[128 x 128] + bias)
// 128-row tile / block of 256 threads; 8x8 acc per thread; k staged in LDS
// chunks of 32 with A transposed to [k][row] so all LDS reads are b128-able.
// LDS = 32*129*4 + 32*128*4 = 33 KB -> 4 blocks/CU.
// ---------------------------------------------------------------------------
__global__ __launch_bounds__(256, 4) void mm_kernel(const float* __restrict__ A,
                                                    const float* __restrict__ W,
                                                    const float* __restrict__ bias,
                                                    float* __restrict__ C, int M) {
    __shared__ float As[32][129];   // [k][row], +1 pad
    __shared__ float Ws[32][128];   // [k][col]
    const int t  = threadIdx.x;
    const int tx = t & 15;          // col group: cols tx*4..+3 and 64+tx*4..+3
    const int ty = t >> 4;          // row group: rows ty*8..+7
    const int row0 = blockIdx.x * 128;

    float acc[8][8];
#pragma unroll
    for (int i = 0; i < 8; ++i)
#pragma unroll
        for (int j = 0; j < 8; ++j) acc[i][j] = 0.f;

    for (int kc = 0; kc < HIDDEN; kc += 32) {
        if (kc) __syncthreads();
        // stage A chunk (transposed): 128 rows x 32 k
#pragma unroll
        for (int pq = 0; pq < 4; ++pq) {
            int id = pq * 256 + t;
            int ro = id >> 3;        // 0..127
            int kq = id & 7;         // 0..7
            int r = row0 + ro;
            if (r > M - 1) r = M - 1;  // clamp: safe read, stores guarded later
            const float4 v = *(const float4*)(A + (size_t)r * HIDDEN + kc + kq * 4);
            As[kq * 4 + 0][ro] = v.x;
            As[kq * 4 + 1][ro] = v.y;
            As[kq * 4 + 2][ro] = v.z;
            As[kq * 4 + 3][ro] = v.w;
        }
        // stage W chunk: 32 k x 128 cols
#pragma unroll
        for (int pq = 0; pq < 4; ++pq) {
            int id = pq * 256 + t;
            int kk = id >> 5;        // 0..31
            int c4 = id & 31;        // 0..31
            *(float4*)(&Ws[kk][c4 * 4]) =
                *(const float4*)(W + (size_t)(kc + kk) * HIDDEN + c4 * 4);
        }
        __syncthreads();
#pragma unroll
        for (int kk = 0; kk < 32; ++kk) {
            float a[8], w[8];
#pragma unroll
            for (int i = 0; i < 8; ++i) a[i] = As[kk][ty * 8 + i];
#pragma unroll
            for (int j = 0; j < 4; ++j) w[j] = Ws[kk][tx * 4 + j];
#pragma unroll
            for (int j = 0; j < 4; ++j) w[4 + j] = Ws[kk][64 + tx * 4 + j];
#pragma unroll
            for (int i = 0; i < 8; ++i)
#pragma unroll
                for (int j = 0; j < 8; ++j) acc[i][j] += a[i] * w[j];
        }
    }

    float bl[8];
#pragma unroll
    for (int j = 0; j < 4; ++j) {
        bl[j]     = bias[tx * 4 + j];
        bl[4 + j] = bias[64 + tx * 4 + j];
    }

#pragma unroll
    for (int i = 0; i < 8; ++i) {
        int r = row0 + ty * 8 + i;
        if (r < M) {
            float4 o0, o1;
            o0.x = fmaxf(acc[i][0] + bl[0], 0.f);
            o0.y = fmaxf(acc[i][1] + bl[1], 0.f);
            o0.z = fmaxf(acc[i][2] + bl[2], 0.f);
            o0.w = fmaxf(acc[i][3] + bl[3], 0.f);
            o1.x = fmaxf(acc[i][4] + bl[4], 0.f);
            o1.y = fmaxf(acc[i][5] + bl[5], 0.f);
            o1.z = fmaxf(acc[i][6] + bl[6], 0.f);
            o1.w = fmaxf(acc[i][7] + bl[7], 0.f);
            *(float4*)(C + (size_t)r * HIDDEN + tx * 4)      = o0;
            *(float4*)(C + (size_t)r * HIDDEN + 64 + tx * 4) = o1;
        }
    }
}

// ---------------------------------------------------------------------------
// Global sum pooling per graph (batch is sorted): block scans 128 contiguous
// nodes, thread f owns feature f, flush one atomicAdd per graph boundary.
// ---------------------------------------------------------------------------
#define POOL_CHUNK 128
__global__ void pool_kernel(const float* __restrict__ X, const int* __restrict__ batch,
                            float* __restrict__ pooled, int layer) {
    const int f = threadIdx.x;  // 0..127
    int start = blockIdx.x * POOL_CHUNK;
    int end = start + POOL_CHUNK;
    if (end > N_NODES) end = N_NODES;
    float acc = 0.f;
    int gcur = batch[start];
    for (int n = start; n < end; ++n) {
        int g = batch[n];
        if (g != gcur) {
            atomicAdd(&pooled[(size_t)gcur * (HIDDEN * N_LAYERS) + layer * HIDDEN + f], acc);
            acc = 0.f;
            gcur = g;
        }
        acc += X[(size_t)n * HIDDEN + f];
    }
    atomicAdd(&pooled[(size_t)gcur * (HIDDEN * N_LAYERS) + layer * HIDDEN + f], acc);
}

// ---------------------------------------------------------------------------
// Classifier head: one block (128 threads) per graph.
// h1 = relu(pooled @ w1 + b1); h2 = relu(h1 @ w2 + b2); out = h2 @ w3 + b3
// ---------------------------------------------------------------------------
__global__ __launch_bounds__(128) void cls_kernel(const float* __restrict__ pooled,
                                                  const float* __restrict__ w1,
                                                  const float* __restrict__ b1,
                                                  const float* __restrict__ w2,
                                                  const float* __restrict__ b2,
                                                  const float* __restrict__ w3,
                                                  const float* __restrict__ b3,
                                                  float* __restrict__ out) {
    __shared__ float hin[HIDDEN * N_LAYERS];  // 384
    __shared__ float h1[HIDDEN];
    __shared__ float red[HIDDEN];
    const int g = blockIdx.x;
    const int t = threadIdx.x;

    for (int i = t; i < HIDDEN * N_LAYERS; i += 128)
        hin[i] = pooled[(size_t)g * (HIDDEN * N_LAYERS) + i];
    __syncthreads();

    float s = 0.f;
    for (int k = 0; k < HIDDEN * N_LAYERS; ++k) s += hin[k] * w1[(size_t)k * HIDDEN + t];
    s = fmaxf(s + b1[t], 0.f);
    h1[t] = s;
    __syncthreads();

    float s2 = 0.f;
    for (int k = 0; k < HIDDEN; ++k) s2 += h1[k] * w2[(size_t)k * HIDDEN + t];
    s2 = fmaxf(s2 + b2[t], 0.f);

    red[t] = s2 * w3[t];
    __syncthreads();
    for (int off = 64; off > 0; off >>= 1) {
        if (t < off) red[t] += red[t + off];
        __syncthreads();
    }
    if (t == 0) out[g] = red[0] + b3[0];
}

// ---------------------------------------------------------------------------
extern "C" void kernel_launch(void* const* d_in, const int* in_sizes, int n_in,
                              void* d_out, int out_size, void* d_ws, size_t ws_size,
                              hipStream_t stream) {
    const float* X     = (const float*)d_in[0];
    const int*   ei    = (const int*)d_in[1];   // [2, N_EDGES]
    const int*   batch = (const int*)d_in[2];
    const float* w1all = (const float*)d_in[3];
    const float* b1all = (const float*)d_in[4];
    const float* w2all = (const float*)d_in[5];
    const float* b2all = (const float*)d_in[6];
    const float* cw1   = (const float*)d_in[7];
    const float* cb1   = (const float*)d_in[8];
    const float* cw2   = (const float*)d_in[9];
    const float* cb2   = (const float*)d_in[10];
    const float* cw3   = (const float*)d_in[11];
    const float* cb3   = (const float*)d_in[12];
    float* out = (float*)d_out;

    const int* src = ei;            // edge_index[0]
    const int* dst = ei + N_EDGES;  // edge_index[1]

    // workspace carve
    char* p = (char*)d_ws;
    auto alloc = [&](size_t bytes) {
        char* r = p;
        p += (bytes + 255) & ~(size_t)255;
        return r;
    };
    float* bufA   = (float*)alloc((size_t)N_NODES * HIDDEN * sizeof(float));
    float* bufB   = (float*)alloc((size_t)N_NODES * HIDDEN * sizeof(float));
    int*   csr    = (int*)alloc((size_t)N_EDGES * sizeof(int));
    int*   rowp   = (int*)alloc((size_t)(N_NODES + 1) * sizeof(int));
    int*   posb   = (int*)alloc((size_t)N_NODES * sizeof(int));
    int*   deg    = (int*)alloc((size_t)N_NODES * sizeof(int));
    float* pooled = (float*)alloc((size_t)N_GRAPHS * HIDDEN * N_LAYERS * sizeof(float));

    hipMemsetAsync(deg, 0, (size_t)N_NODES * sizeof(int), stream);
    hipMemsetAsync(pooled, 0, (size_t)N_GRAPHS * HIDDEN * N_LAYERS * sizeof(float), stream);

    deg_kernel<<<(N_EDGES + 255) / 256, 256, 0, stream>>>(dst, deg);
    scan_kernel<<<1, 1024, 0, stream>>>(deg, rowp);
    hipMemcpyAsync(posb, rowp, (size_t)N_NODES * sizeof(int),
                   hipMemcpyDeviceToDevice, stream);
    scatter_kernel<<<(N_EDGES + 255) / 256, 256, 0, stream>>>(src, dst, posb, csr);

    // ping-pong buffers: gather out -> mm1 out -> mm2 out (= next layer input)
    const float* Xin = X;
    float* gout[3]   = {bufA, bufB, bufA};
    float* m1out[3]  = {bufB, bufA, bufB};
    float* m2out[3]  = {bufA, bufB, bufA};

    const int mm_grid   = (N_NODES + 127) / 128;
    const int gat_grid  = (N_NODES + 3) / 4;      // 4 waves/block, 1 wave/node
    const int pool_grid = (N_NODES + POOL_CHUNK - 1) / POOL_CHUNK;

    for (int l = 0; l < N_LAYERS; ++l) {
        gather_kernel<<<gat_grid, 256, 0, stream>>>(Xin, gout[l], rowp, csr);
        mm_kernel<<<mm_grid, 256, 0, stream>>>(gout[l],
                                               w1all + (size_t)l * HIDDEN * HIDDEN,
                                               b1all + (size_t)l * HIDDEN,
                                               m1out[l], N_NODES);
        mm_kernel<<<mm_grid, 256, 0, stream>>>(m1out[l],
                                               w2all + (size_t)l * HIDDEN * HIDDEN,
                                               b2all + (size_t)l * HIDDEN,
                                               m2out[l], N_NODES);
        pool_kernel<<<pool_grid, POOL_CHUNK, 0, stream>>>(m2out[l], batch, pooled, l);
        Xin = m2out[l];
    }

    cls_kernel<<<N_GRAPHS, 128, 0, stream>>>(pooled, cw1, cb1, cw2, cb2, cw3, cb3, out);
}

// Round 2
// 1195.508 us; speedup vs baseline: 1.1356x; 1.1356x over previous
//
#include <hip/hip_runtime.h>
#include <cstddef>
#include <cstdint>

#define N_NODES   100000
#define N_EDGES   1600000
#define N_GRAPHS  512
#define HIDDEN    128
#define N_LAYERS  3

#define SCAN_BS   1024
#define SCAN_NB   ((N_NODES + SCAN_BS - 1) / SCAN_BS)   // 98

// ---------------------------------------------------------------------------
// CSR build (by dst): histogram -> hierarchical scan -> scatter
// ---------------------------------------------------------------------------
__global__ void deg_kernel(const int* __restrict__ dst, int* __restrict__ deg) {
    int e = blockIdx.x * blockDim.x + threadIdx.x;
    if (e < N_EDGES) atomicAdd(&deg[dst[e]], 1);
}

// per-block inclusive scan of deg -> scanned; per-block totals -> bsums
__global__ __launch_bounds__(SCAN_BS) void scan_blocks_kernel(const int* __restrict__ deg,
                                                              int* __restrict__ scanned,
                                                              int* __restrict__ bsums) {
    __shared__ int tmp[SCAN_BS];
    const int t = threadIdx.x;
    const int i = blockIdx.x * SCAN_BS + t;
    int v = (i < N_NODES) ? deg[i] : 0;
    tmp[t] = v;
    __syncthreads();
#pragma unroll
    for (int off = 1; off < SCAN_BS; off <<= 1) {
        int u = (t >= off) ? tmp[t - off] : 0;
        __syncthreads();
        tmp[t] += u;
        __syncthreads();
    }
    if (i < N_NODES) scanned[i] = tmp[t];
    if (t == SCAN_BS - 1) bsums[blockIdx.x] = tmp[t];
}

// single small block: in-place inclusive scan of the 98 block sums
__global__ __launch_bounds__(128) void scan_tops_kernel(int* __restrict__ bsums) {
    __shared__ int tmp[128];
    const int t = threadIdx.x;
    tmp[t] = (t < SCAN_NB) ? bsums[t] : 0;
    __syncthreads();
#pragma unroll
    for (int off = 1; off < 128; off <<= 1) {
        int u = (t >= off) ? tmp[t - off] : 0;
        __syncthreads();
        tmp[t] += u;
        __syncthreads();
    }
    if (t < SCAN_NB) bsums[t] = tmp[t];
}

// row_ptr[i+1] = offset(b) + scanned[i];  posb[i] = row_ptr[i] (row start)
__global__ __launch_bounds__(SCAN_BS) void scan_finalize_kernel(const int* __restrict__ deg,
                                                                const int* __restrict__ scanned,
                                                                const int* __restrict__ bsums,
                                                                int* __restrict__ row_ptr,
                                                                int* __restrict__ posb) {
    const int b = blockIdx.x;
    const int i = b * SCAN_BS + threadIdx.x;
    if (i >= N_NODES) return;
    const int off = (b > 0) ? bsums[b - 1] : 0;
    const int inc = off + scanned[i];
    row_ptr[i + 1] = inc;
    posb[i] = inc - deg[i];
    if (i == 0) row_ptr[0] = 0;
}

__global__ void scatter_kernel(const int* __restrict__ src, const int* __restrict__ dst,
                               int* __restrict__ pos, int* __restrict__ csr_src) {
    int e = blockIdx.x * blockDim.x + threadIdx.x;
    if (e < N_EDGES) {
        int p = atomicAdd(&pos[dst[e]], 1);
        csr_src[p] = src[e];
    }
}

// ---------------------------------------------------------------------------
// GIN aggregation: Z[i] = X[i] + sum_{j in N_in(i)} X[j]
// one wave (64 lanes) per node, float2 per lane => 512B coalesced row reads
// ---------------------------------------------------------------------------
__global__ void gather_kernel(const float* __restrict__ X, float* __restrict__ Z,
                              const int* __restrict__ row_ptr,
                              const int* __restrict__ csr_src) {
    int wave = (blockIdx.x * blockDim.x + threadIdx.x) >> 6;
    int lane = threadIdx.x & 63;
    if (wave >= N_NODES) return;
    const int i = wave;
    float2 acc = ((const float2*)(X + (size_t)i * HIDDEN))[lane];
    int k = row_ptr[i];
    const int end = row_ptr[i + 1];
    // 4-deep unroll: 4 independent row loads in flight to hide LLC latency
    for (; k + 4 <= end; k += 4) {
        int n0 = csr_src[k + 0];
        int n1 = csr_src[k + 1];
        int n2 = csr_src[k + 2];
        int n3 = csr_src[k + 3];
        float2 v0 = ((const float2*)(X + (size_t)n0 * HIDDEN))[lane];
        float2 v1 = ((const float2*)(X + (size_t)n1 * HIDDEN))[lane];
        float2 v2 = ((const float2*)(X + (size_t)n2 * HIDDEN))[lane];
        float2 v3 = ((const float2*)(X + (size_t)n3 * HIDDEN))[lane];
        acc.x += v0.x + v1.x + v2.x + v3.x;
        acc.y += v0.y + v1.y + v2.y + v3.y;
    }
    for (; k < end; ++k) {
        int n = csr_src[k];
        float2 v = ((const float2*)(X + (size_t)n * HIDDEN))[lane];
        acc.x += v.x;
        acc.y += v.y;
    }
    ((float2*)(Z + (size_t)i * HIDDEN))[lane] = acc;
}

// ---------------------------------------------------------------------------
// C[M x 128] = relu(A[M x 128] @ W[128 x 128] + bias)
// 128-row tile / block of 256 threads; 8x8 acc per thread; k staged in LDS
// chunks of 32 with A transposed to [k][row] so all LDS reads are b128-able.
// LDS = 32*129*4 + 32*128*4 = 33 KB -> 4 blocks/CU.
// ---------------------------------------------------------------------------
__global__ __launch_bounds__(256, 4) void mm_kernel(const float* __restrict__ A,
                                                    const float* __restrict__ W,
                                                    const float* __restrict__ bias,
                                                    float* __restrict__ C, int M) {
    __shared__ float As[32][129];   // [k][row], +1 pad
    __shared__ float Ws[32][128];   // [k][col]
    const int t  = threadIdx.x;
    const int tx = t & 15;          // col group: cols tx*4..+3 and 64+tx*4..+3
    const int ty = t >> 4;          // row group: rows ty*8..+7
    const int row0 = blockIdx.x * 128;

    float acc[8][8];
#pragma unroll
    for (int i = 0; i < 8; ++i)
#pragma unroll
        for (int j = 0; j < 8; ++j) acc[i][j] = 0.f;

    for (int kc = 0; kc < HIDDEN; kc += 32) {
        if (kc) __syncthreads();
        // stage A chunk (transposed): 128 rows x 32 k
#pragma unroll
        for (int pq = 0; pq < 4; ++pq) {
            int id = pq * 256 + t;
            int ro = id >> 3;        // 0..127
            int kq = id & 7;         // 0..7
            int r = row0 + ro;
            if (r > M - 1) r = M - 1;  // clamp: safe read, stores guarded later
            const float4 v = *(const float4*)(A + (size_t)r * HIDDEN + kc + kq * 4);
            As[kq * 4 + 0][ro] = v.x;
            As[kq * 4 + 1][ro] = v.y;
            As[kq * 4 + 2][ro] = v.z;
            As[kq * 4 + 3][ro] = v.w;
        }
        // stage W chunk: 32 k x 128 cols
#pragma unroll
        for (int pq = 0; pq < 4; ++pq) {
            int id = pq * 256 + t;
            int kk = id >> 5;        // 0..31
            int c4 = id & 31;        // 0..31
            *(float4*)(&Ws[kk][c4 * 4]) =
                *(const float4*)(W + (size_t)(kc + kk) * HIDDEN + c4 * 4);
        }
        __syncthreads();
#pragma unroll
        for (int kk = 0; kk < 32; ++kk) {
            float a[8], w[8];
#pragma unroll
            for (int i = 0; i < 8; ++i) a[i] = As[kk][ty * 8 + i];
#pragma unroll
            for (int j = 0; j < 4; ++j) w[j] = Ws[kk][tx * 4 + j];
#pragma unroll
            for (int j = 0; j < 4; ++j) w[4 + j] = Ws[kk][64 + tx * 4 + j];
#pragma unroll
            for (int i = 0; i < 8; ++i)
#pragma unroll
                for (int j = 0; j < 8; ++j) acc[i][j] += a[i] * w[j];
        }
    }

    float bl[8];
#pragma unroll
    for (int j = 0; j < 4; ++j) {
        bl[j]     = bias[tx * 4 + j];
        bl[4 + j] = bias[64 + tx * 4 + j];
    }

#pragma unroll
    for (int i = 0; i < 8; ++i) {
        int r = row0 + ty * 8 + i;
        if (r < M) {
            float4 o0, o1;
            o0.x = fmaxf(acc[i][0] + bl[0], 0.f);
            o0.y = fmaxf(acc[i][1] + bl[1], 0.f);
            o0.z = fmaxf(acc[i][2] + bl[2], 0.f);
            o0.w = fmaxf(acc[i][3] + bl[3], 0.f);
            o1.x = fmaxf(acc[i][4] + bl[4], 0.f);
            o1.y = fmaxf(acc[i][5] + bl[5], 0.f);
            o1.z = fmaxf(acc[i][6] + bl[6], 0.f);
            o1.w = fmaxf(acc[i][7] + bl[7], 0.f);
            *(float4*)(C + (size_t)r * HIDDEN + tx * 4)      = o0;
            *(float4*)(C + (size_t)r * HIDDEN + 64 + tx * 4) = o1;
        }
    }
}

// ---------------------------------------------------------------------------
// Global sum pooling per graph (batch is sorted): block scans 128 contiguous
// nodes, thread f owns feature f, flush one atomicAdd per graph boundary.
// ---------------------------------------------------------------------------
#define POOL_CHUNK 128
__global__ void pool_kernel(const float* __restrict__ X, const int* __restrict__ batch,
                            float* __restrict__ pooled, int layer) {
    const int f = threadIdx.x;  // 0..127
    int start = blockIdx.x * POOL_CHUNK;
    int end = start + POOL_CHUNK;
    if (end > N_NODES) end = N_NODES;
    float acc = 0.f;
    int gcur = batch[start];
    for (int n = start; n < end; ++n) {
        int g = batch[n];
        if (g != gcur) {
            atomicAdd(&pooled[(size_t)gcur * (HIDDEN * N_LAYERS) + layer * HIDDEN + f], acc);
            acc = 0.f;
            gcur = g;
        }
        acc += X[(size_t)n * HIDDEN + f];
    }
    atomicAdd(&pooled[(size_t)gcur * (HIDDEN * N_LAYERS) + layer * HIDDEN + f], acc);
}

// ---------------------------------------------------------------------------
// Classifier head: one block (128 threads) per graph.
// ---------------------------------------------------------------------------
__global__ __launch_bounds__(128) void cls_kernel(const float* __restrict__ pooled,
                                                  const float* __restrict__ w1,
                                                  const float* __restrict__ b1,
                                                  const float* __restrict__ w2,
                                                  const float* __restrict__ b2,
                                                  const float* __restrict__ w3,
                                                  const float* __restrict__ b3,
                                                  float* __restrict__ out) {
    __shared__ float hin[HIDDEN * N_LAYERS];  // 384
    __shared__ float h1[HIDDEN];
    __shared__ float red[HIDDEN];
    const int g = blockIdx.x;
    const int t = threadIdx.x;

    for (int i = t; i < HIDDEN * N_LAYERS; i += 128)
        hin[i] = pooled[(size_t)g * (HIDDEN * N_LAYERS) + i];
    __syncthreads();

    float s = 0.f;
    for (int k = 0; k < HIDDEN * N_LAYERS; ++k) s += hin[k] * w1[(size_t)k * HIDDEN + t];
    s = fmaxf(s + b1[t], 0.f);
    h1[t] = s;
    __syncthreads();

    float s2 = 0.f;
    for (int k = 0; k < HIDDEN; ++k) s2 += h1[k] * w2[(size_t)k * HIDDEN + t];
    s2 = fmaxf(s2 + b2[t], 0.f);

    red[t] = s2 * w3[t];
    __syncthreads();
    for (int off = 64; off > 0; off >>= 1) {
        if (t < off) red[t] += red[t + off];
        __syncthreads();
    }
    if (t == 0) out[g] = red[0] + b3[0];
}

// ---------------------------------------------------------------------------
extern "C" void kernel_launch(void* const* d_in, const int* in_sizes, int n_in,
                              void* d_out, int out_size, void* d_ws, size_t ws_size,
                              hipStream_t stream) {
    const float* X     = (const float*)d_in[0];
    const int*   ei    = (const int*)d_in[1];   // [2, N_EDGES]
    const int*   batch = (const int*)d_in[2];
    const float* w1all = (const float*)d_in[3];
    const float* b1all = (const float*)d_in[4];
    const float* w2all = (const float*)d_in[5];
    const float* b2all = (const float*)d_in[6];
    const float* cw1   = (const float*)d_in[7];
    const float* cb1   = (const float*)d_in[8];
    const float* cw2   = (const float*)d_in[9];
    const float* cb2   = (const float*)d_in[10];
    const float* cw3   = (const float*)d_in[11];
    const float* cb3   = (const float*)d_in[12];
    float* out = (float*)d_out;

    const int* src = ei;            // edge_index[0]
    const int* dst = ei + N_EDGES;  // edge_index[1]

    // workspace carve
    char* p = (char*)d_ws;
    auto alloc = [&](size_t bytes) {
        char* r = p;
        p += (bytes + 255) & ~(size_t)255;
        return r;
    };
    float* bufA    = (float*)alloc((size_t)N_NODES * HIDDEN * sizeof(float));
    float* bufB    = (float*)alloc((size_t)N_NODES * HIDDEN * sizeof(float));
    int*   csr     = (int*)alloc((size_t)N_EDGES * sizeof(int));
    int*   rowp    = (int*)alloc((size_t)(N_NODES + 1) * sizeof(int));
    int*   posb    = (int*)alloc((size_t)N_NODES * sizeof(int));
    int*   deg     = (int*)alloc((size_t)N_NODES * sizeof(int));
    int*   scanned = (int*)alloc((size_t)N_NODES * sizeof(int));
    int*   bsums   = (int*)alloc((size_t)SCAN_NB * sizeof(int));
    float* pooled  = (float*)alloc((size_t)N_GRAPHS * HIDDEN * N_LAYERS * sizeof(float));

    hipMemsetAsync(deg, 0, (size_t)N_NODES * sizeof(int), stream);
    hipMemsetAsync(pooled, 0, (size_t)N_GRAPHS * HIDDEN * N_LAYERS * sizeof(float), stream);

    deg_kernel<<<(N_EDGES + 255) / 256, 256, 0, stream>>>(dst, deg);
    scan_blocks_kernel<<<SCAN_NB, SCAN_BS, 0, stream>>>(deg, scanned, bsums);
    scan_tops_kernel<<<1, 128, 0, stream>>>(bsums);
    scan_finalize_kernel<<<SCAN_NB, SCAN_BS, 0, stream>>>(deg, scanned, bsums, rowp, posb);
    scatter_kernel<<<(N_EDGES + 255) / 256, 256, 0, stream>>>(src, dst, posb, csr);

    // ping-pong buffers: gather out -> mm1 out -> mm2 out (= next layer input)
    const float* Xin = X;
    float* gout[3]   = {bufA, bufB, bufA};
    float* m1out[3]  = {bufB, bufA, bufB};
    float* m2out[3]  = {bufA, bufB, bufA};

    const int mm_grid   = (N_NODES + 127) / 128;
    const int gat_grid  = (N_NODES + 3) / 4;      // 4 waves/block, 1 wave/node
    const int pool_grid = (N_NODES + POOL_CHUNK - 1) / POOL_CHUNK;

    for (int l = 0; l < N_LAYERS; ++l) {
        gather_kernel<<<gat_grid, 256, 0, stream>>>(Xin, gout[l], rowp, csr);
        mm_kernel<<<mm_grid, 256, 0, stream>>>(gout[l],
                                               w1all + (size_t)l * HIDDEN * HIDDEN,
                                               b1all + (size_t)l * HIDDEN,
                                               m1out[l], N_NODES);
        mm_kernel<<<mm_grid, 256, 0, stream>>>(m1out[l],
                                               w2all + (size_t)l * HIDDEN * HIDDEN,
                                               b2all + (size_t)l * HIDDEN,
                                               m2out[l], N_NODES);
        pool_kernel<<<pool_grid, POOL_CHUNK, 0, stream>>>(m2out[l], batch, pooled, l);
        Xin = m2out[l];
    }

    cls_kernel<<<N_GRAPHS, 128, 0, stream>>>(pooled, cw1, cb1, cw2, cb2, cw3, cb3, out);
}